// Round 2
// baseline (225.293 us; speedup 1.0000x reference)
//
#include <hip/hip_runtime.h>

// MCANet: out = x * sigmoid(w1d[c, center] * mean_{h,w}(x[b,c,h,w]))
// The conv1x1+softmax branch in the reference is dead code (del y).
// x: (16, 512, 64, 64) f32; w1d: (512, 5) f32; center tap index = 2.
//
// Streaming kernel: 134 MB read + 134 MB write, register-resident between
// the reduction and the scale (x is read exactly once). Non-temporal
// loads/stores: zero reuse, working set (268 MB) > LLC (256 MB).
//
// Structure: ONE WAVE PER PLANE, barrier-free. The 4-waves-per-plane
// version coupled all waves through vmcnt(0)-drain + 2x __syncthreads +
// a tid==0 sigmoid serialization before any store could issue. Here each
// wave is fully independent: 16 outstanding vf4 loads/lane, packed-add
// accumulate, 6-step __shfl_xor butterfly (all 64 lanes end with the
// plane sum), redundant per-lane sigmoid, immediate NT stores.
// Data: 16 vf4/lane = 64 VGPRs, all statically indexed -> registers.

#define NC 512
#define HW 4096           // 64*64
#define PER_LANE 16       // (HW/4) vf4s / 64 lanes

typedef float vf4 __attribute__((ext_vector_type(4)));

__global__ __launch_bounds__(256) void mcanet_gate_kernel(
    const float* __restrict__ x,
    const float* __restrict__ w1d,
    float* __restrict__ out)
{
    const int wave  = threadIdx.x >> 6;
    const int lane  = threadIdx.x & 63;
    const int plane = (blockIdx.x << 2) + wave;   // b*NC + c
    const int c = plane & (NC - 1);

    // Tiny gate-weight load first: 10 KB table, L2-resident after the
    // first touches; its latency hides under the 16 plane loads.
    const float wc = w1d[c * 5 + 2];

    const long long base = (long long)plane * HW;
    const vf4* __restrict__ xin = (const vf4*)(x + base);
    vf4* __restrict__ o = (vf4*)(out + base);

    // Wave covers its 16 KB plane: lane i reads vf4 (lane + 64*k),
    // i.e. 1 KB contiguous per load instruction, 16 in flight.
    vf4 v[PER_LANE];
    #pragma unroll
    for (int i = 0; i < PER_LANE; ++i)
        v[i] = __builtin_nontemporal_load(xin + lane + (i << 6));

    // Packed accumulate (compiler emits v_pk_add_f32), then horizontal.
    vf4 acc = v[0];
    #pragma unroll
    for (int i = 1; i < PER_LANE; ++i)
        acc += v[i];
    float s = (acc.x + acc.y) + (acc.z + acc.w);

    // Butterfly: every lane ends with the full plane sum.
    #pragma unroll
    for (int off = 32; off > 0; off >>= 1)
        s += __shfl_xor(s, off, 64);

    const float zc = wc * (s * (1.0f / (float)HW));
    const float g  = 1.0f / (1.0f + __expf(-zc));

    #pragma unroll
    for (int i = 0; i < PER_LANE; ++i) {
        vf4 r = v[i] * g;
        __builtin_nontemporal_store(r, o + lane + (i << 6));
    }
}

extern "C" void kernel_launch(void* const* d_in, const int* in_sizes, int n_in,
                              void* d_out, int out_size, void* d_ws, size_t ws_size,
                              hipStream_t stream) {
    const float* x   = (const float*)d_in[0];  // (16,512,64,64)
    // d_in[1] = w1x1 (unused), d_in[2] = b1x1 (unused)
    const float* w1d = (const float*)d_in[3];  // (512,5)
    float* out = (float*)d_out;

    const int planes = 16 * NC;                // 8192 planes
    mcanet_gate_kernel<<<planes / 4, 256, 0, stream>>>(x, w1d, out);
}